// Round 6
// baseline (801.472 us; speedup 1.0000x reference)
//
#include <hip/hip_runtime.h>

#define BS 256       // 4 waves/block, each with a private LDS slab. Zero barriers.
#define NFEAT 121
#define SMAX 37      // uniform LDS row stride (floats), all phases; odd -> conflict-free
                     // slab/wave = 64*37*4 = 9,472 B; block = 37,888 B -> 4 blocks/CU (50% occ)

// 4 column phases (3 boundary lines/row, mostly L2-merged; R0 measured +14.5% for 2):
//   A: f0..f5 -> cols [0,36)   B: f6,f7 -> cols [36,64)
//   C: f8,f9 -> cols [64,100)  D: f10  -> cols [100,121)
// Compute is ROLLED (j-loop #pragma unroll 1) writing straight to LDS: total kernel
// text ~8 KB << 32 KB I$. R4/R5's fully-unrolled ~60 KB stream was I-fetch-bound
// (VALUBusy 25% vs 46% rolled, insensitive to occupancy). prev[] is refreshed from
// LDS with static-index copies -> stays in VGPRs.

__device__ __forceinline__ float dot3(const float* __restrict__ c, float x, float y, float z) {
    return fmaf(c[2], z, fmaf(c[1], y, c[0] * x));
}

// srow[colofs+j] = sum_a prev[a] * dot3(cob[j,3a..], f1)
// j rolled (small I-cache; crow wave-uniform -> s_load), a unrolled (prev in regs).
template<int LL, bool UPDATE_PREV>
__device__ __forceinline__ void step_l(const float* __restrict__ cob,
                                       float* srow, int colofs,
                                       float f1x, float f1y, float f1z,
                                       float* prev) {
    constexpr int IN  = 2 * LL - 1;
    constexpr int OUT = 2 * LL + 1;
    #pragma unroll 1
    for (int j = 0; j < OUT; ++j) {
        const float* __restrict__ crow = cob + j * (3 * IN);
        float acc = 0.f;
        #pragma unroll
        for (int a = 0; a < IN; ++a)
            acc = fmaf(prev[a], dot3(crow + 3 * a, f1x, f1y, f1z), acc);
        srow[colofs + j] = acc;
    }
    if (UPDATE_PREV) {
        #pragma unroll
        for (int j = 0; j < OUT; ++j) prev[j] = srow[colofs + j];
    }
}

// Per-wave drain of one phase: lanes 0..W-1 each own a column; addresses advance by
// compile-time constants (no per-element div / 64-bit math). Stores are runs of W
// consecutive floats per row -> coalesced. No barrier: same-wave LDS ops are in-order,
// and the slab aliasing (srow vs slab, both from sbuf) is visible to the compiler.
template<int W, int C0>
__device__ __forceinline__ void wave_drain(const float* slab, float* __restrict__ outw,
                                           int wrows, int lane) {
    if (lane < W) {
        const float* sp = slab + lane;
        float* __restrict__ gp = outw + C0 + lane;
        if (wrows == 64) {
            #pragma unroll 16
            for (int r = 0; r < 64; ++r)
                gp[r * NFEAT] = sp[r * SMAX];
        } else {
            #pragma unroll 4
            for (int r = 0; r < 64; ++r)
                if (r < wrows) gp[r * NFEAT] = sp[r * SMAX];
        }
    }
}

__global__ __launch_bounds__(BS) void harmonic_kernel(
    const float* __restrict__ points,
    const float* __restrict__ cob1,  const float* __restrict__ cob2,
    const float* __restrict__ cob3,  const float* __restrict__ cob4,
    const float* __restrict__ cob5,  const float* __restrict__ cob6,
    const float* __restrict__ cob7,  const float* __restrict__ cob8,
    const float* __restrict__ cob9,  const float* __restrict__ cob10,
    float* __restrict__ out, int N) {
    __shared__ float sbuf[(BS / 64) * 64 * SMAX];   // 37,888 B

    const int t    = threadIdx.x;
    const int lane = t & 63;
    const int w    = t >> 6;
    const long long wbase = (long long)blockIdx.x * BS + ((long long)w << 6);
    const long long p     = wbase + lane;
    const bool active = p < (long long)N;
    long long nv = (long long)N - wbase;
    const int wrows = nv >= 64 ? 64 : (nv > 0 ? (int)nv : 0);

    float px = 0.f, py = 0.f, pz = 0.f;
    if (active) {
        px = points[p * 3 + 0];
        py = points[p * 3 + 1];
        pz = points[p * 3 + 2];
    }

    const float f1x = dot3(cob1 + 0, px, py, pz);
    const float f1y = dot3(cob1 + 3, px, py, pz);
    const float f1z = dot3(cob1 + 6, px, py, pz);

    float prev[21];
    prev[0] = f1x; prev[1] = f1y; prev[2] = f1z;

    float* slab = sbuf + w * (64 * SMAX);   // this wave's 64-row slab
    float* srow = slab + lane * SMAX;       // this thread's row (aliases slab)
    float* __restrict__ outw = out + wbase * NFEAT;

    // ---- Phase A: f0..f5 -> cols [0,36) ----
    srow[0] = 1.f;
    srow[1] = f1x; srow[2] = f1y; srow[3] = f1z;
    step_l<2, true>(cob2, srow, 4,  f1x, f1y, f1z, prev);
    step_l<3, true>(cob3, srow, 9,  f1x, f1y, f1z, prev);
    step_l<4, true>(cob4, srow, 16, f1x, f1y, f1z, prev);
    step_l<5, true>(cob5, srow, 25, f1x, f1y, f1z, prev);
    wave_drain<36, 0>(slab, outw, wrows, lane);

    // ---- Phase B: f6,f7 -> cols [36,64) ----
    step_l<6, true>(cob6, srow, 0,  f1x, f1y, f1z, prev);
    step_l<7, true>(cob7, srow, 13, f1x, f1y, f1z, prev);
    wave_drain<28, 36>(slab, outw, wrows, lane);

    // ---- Phase C: f8,f9 -> cols [64,100) ----
    step_l<8, true>(cob8, srow, 0,  f1x, f1y, f1z, prev);
    step_l<9, true>(cob9, srow, 17, f1x, f1y, f1z, prev);
    wave_drain<36, 64>(slab, outw, wrows, lane);

    // ---- Phase D: f10 -> cols [100,121) ----
    step_l<10, false>(cob10, srow, 0, f1x, f1y, f1z, prev);
    wave_drain<21, 100>(slab, outw, wrows, lane);
}

extern "C" void kernel_launch(void* const* d_in, const int* in_sizes, int n_in,
                              void* d_out, int out_size, void* d_ws, size_t ws_size,
                              hipStream_t stream) {
    const float* points = (const float*)d_in[0];
    const float* cob[10];
    for (int i = 0; i < 10; ++i) cob[i] = (const float*)d_in[1 + i];
    float* out = (float*)d_out;
    const int N = in_sizes[0] / 3;

    const int grid = (N + BS - 1) / BS;
    harmonic_kernel<<<grid, BS, 0, stream>>>(
        points,
        cob[0], cob[1], cob[2], cob[3], cob[4],
        cob[5], cob[6], cob[7], cob[8], cob[9],
        out, N);
}